// Round 8
// baseline (373.045 us; speedup 1.0000x reference)
//
#include <hip/hip_runtime.h>

// inputs: (B=8, C=2, D=96, H=64, W=64) f32
// weight/bias: (F=8, C=2, d=3, h=60, w=64) f32
// out: (B=8, F=8, Dout=94, h=60, w=64) f32
#define B_ 8
#define C_ 2
#define D_ 96
#define H_ 64
#define W_ 64
#define F_ 8
#define KD 3
#define h_ 60
#define Dout_ 94
#define PLANE (h_ * W_)        // 3840 floats
#define NCH (PLANE / 4)        // 960 float4 per output plane
#define INCH (H_ * W_ / 4)     // 1024 float4 per input plane
#define BOXN (62 * 16)         // 992 float4 per box buffer

__device__ __forceinline__ float4 f4fma(float4 a, float4 b, float4 c) {
    c.x += a.x * b.x; c.y += a.y * b.y; c.z += a.z * b.z; c.w += a.w * b.w;
    return c;
}
__device__ __forceinline__ float4 f4add3(float4 a, float4 b, float4 c) {
    float4 o;
    o.x = a.x + b.x + c.x; o.y = a.y + b.y + c.y;
    o.z = a.z + b.z + c.z; o.w = a.w + b.w + c.w;
    return o;
}

// Horizontal 3-tap sum via lane shuffles; c4 = float4-column 0..15 within a
// 16-lane row group. Boundary columns contribute zero. Call from ALL lanes.
__device__ __forceinline__ float4 hsum3(float4 V, int c4) {
    const int lane = threadIdx.x & 63;
    float lw = __shfl(V.w, (lane + 63) & 63, 64);
    float rx = __shfl(V.x, (lane + 1) & 63, 64);
    if (c4 == 0) lw = 0.f;
    if (c4 == 15) rx = 0.f;
    float4 o;
    o.x = lw + V.x + V.y;
    o.y = V.x + V.y + V.z;
    o.z = V.y + V.z + V.w;
    o.w = V.z + V.w + rx;
    return o;
}

// ---------------------------------------------------------------------------
// bb[f] = Box3x3( sum_{c,z} bias[f,c,z] )  (unscaled). 8 blocks.
// ---------------------------------------------------------------------------
__global__ __launch_bounds__(256) void k_bb(const float* __restrict__ bs,
                                            float* __restrict__ bb) {
    const int f = blockIdx.x;
    const int tid = threadIdx.x;
    __shared__ float4 R[BOXN];  // rows 0..61, rows 0 and 61 zeroed
    if (tid < 32) {
        const int r = (tid >> 4) ? 61 : 0;
        R[r * 16 + (tid & 15)] = make_float4(0, 0, 0, 0);
    }
    const float4* bp = (const float4*)(bs + (size_t)f * (C_ * KD * PLANE));
#pragma unroll
    for (int k = 0; k < 4; ++k) {
        const int e = tid + 256 * k;
        if (e < NCH) {
            float4 s = make_float4(0, 0, 0, 0);
#pragma unroll
            for (int s6 = 0; s6 < 6; ++s6) {
                const float4 v = bp[s6 * NCH + e];
                s.x += v.x; s.y += v.y; s.z += v.z; s.w += v.w;
            }
            R[((e >> 4) + 1) * 16 + (e & 15)] = s;
        }
    }
    __syncthreads();
    float4* ob = (float4*)(bb + (size_t)f * PLANE);
#pragma unroll
    for (int k = 0; k < 4; ++k) {
        const int e = tid + 256 * k;
        const int c4 = e & 15;
        float4 V = make_float4(0, 0, 0, 0);
        if (e < NCH) {
            const int row = e >> 4;
            V = f4add3(R[row * 16 + c4], R[(row + 1) * 16 + c4],
                       R[(row + 2) * 16 + c4]);
        }
        float4 o = hsum3(V, c4);
        if (e < NCH) ob[e] = o;
    }
}

// ---------------------------------------------------------------------------
// Fused main kernel. Block = (b, dout); 1024 threads (1 chunk/thread, 960
// active); 752 blocks; b = bx&7 so co-scheduled blocks on one XCD share b
// (input 3.1 MB/b + weights 1.5 MB fit the 4 MB XCD L2).
//
// Phase A/B (c=0,1): stage 3 raw input planes in LDS (48 KB), barrier,
//   per-thread vertical 5-sums into 3 transient regs, FMA against 8f x 3z
//   weight chunks (L2 stream) into acc[8] ACCUMULATORS (not sinkable).
// Phase C: per f: 3x3 box via ping-pong buffers overlaid on the staging
//   LDS (1 barrier/f), + bb, *0.25, leaky-relu, contiguous plane store.
// ---------------------------------------------------------------------------
__global__ __launch_bounds__(1024) void k_main(const float* __restrict__ in,
                                               const float* __restrict__ wt,
                                               const float* __restrict__ bb,
                                               float* __restrict__ out) {
    const int bx = blockIdx.x;
    const int b = bx & 7;          // XCD-affinity swizzle
    const int dout = bx >> 3;      // 0..93
    const int tid = threadIdx.x;

    __shared__ float4 S[3 * INCH];  // 49,152 B; staging, later 2 box buffers

    const float4 z4 = make_float4(0, 0, 0, 0);
    const int e = tid;              // chunk id
    const int row = e >> 4;         // 0..63
    const int c4 = e & 15;
    const bool act = (e < NCH);     // e < 960

    const float4* in4 = (const float4*)in;
    const float4* wt4 = (const float4*)wt;
    const float4* bb4 = (const float4*)bb;
    float4* out4 = (float4*)out;

    float4 acc[F_];
#pragma unroll
    for (int f = 0; f < F_; ++f) acc[f] = z4;

#pragma unroll
    for (int c = 0; c < C_; ++c) {
        // Stage 3 input planes (dout+z), coalesced, 3 loads/thread.
#pragma unroll
        for (int z = 0; z < KD; ++z)
            S[z * INCH + tid] =
                in4[((size_t)(b * C_ + c) * D_ + dout + z) * INCH + tid];
        __syncthreads();

        // Vertical 5-sum into transient registers.
        float4 s2v[KD];
#pragma unroll
        for (int z = 0; z < KD; ++z) {
            float4 s = z4;
            if (act) {
                s = S[z * INCH + row * 16 + c4];
#pragma unroll
                for (int j = 1; j < 5; ++j) {
                    const float4 v = S[z * INCH + (row + j) * 16 + c4];
                    s.x += v.x; s.y += v.y; s.z += v.z; s.w += v.w;
                }
            }
            s2v[z] = s;
        }

        // FMA against all 8 f (weights stream from XCD-L2-resident wt).
#pragma unroll
        for (int f = 0; f < F_; ++f)
#pragma unroll
            for (int z = 0; z < KD; ++z) {
                const float4 w =
                    act ? wt4[(size_t)((f * C_ + c) * KD + z) * NCH + e] : z4;
                acc[f] = f4fma(w, s2v[z], acc[f]);
            }
        __syncthreads();   // staging region reused (c=1 stage / box overlay)
    }

    // Phase C. Box buffers overlay S: Box0 = S[0..991], Box1 = S[992..1983].
    // Idle threads (960..1023) zero the 64 halo chunks (rows 0,61 x 2 bufs).
    if (tid >= NCH) {
        const int idx = tid - NCH;        // 0..63
        const int buf = idx >> 5;         // 0..1
        const int i2 = idx & 31;
        const int r = (i2 >> 4) ? 61 : 0;
        S[buf * BOXN + r * 16 + (i2 & 15)] = z4;
    }

#pragma unroll
    for (int f = 0; f < F_; ++f) {
        const float4 bbv = act ? bb4[(size_t)f * NCH + e] : z4;
        float4* Bx = S + (f & 1) * BOXN;
        if (act) Bx[(row + 1) * 16 + c4] = acc[f];
        __syncthreads();                  // one barrier per f (ping-pong)

        float4 V = z4;
        if (act)
            V = f4add3(Bx[row * 16 + c4], Bx[(row + 1) * 16 + c4],
                       Bx[(row + 2) * 16 + c4]);
        float4 o = hsum3(V, c4);          // uniform: no shuffle divergence
        if (act) {
            o.x = 0.25f * (o.x + bbv.x);
            o.y = 0.25f * (o.y + bbv.y);
            o.z = 0.25f * (o.z + bbv.z);
            o.w = 0.25f * (o.w + bbv.w);
            o.x = (o.x > 0.f) ? o.x : 0.2f * o.x;
            o.y = (o.y > 0.f) ? o.y : 0.2f * o.y;
            o.z = (o.z > 0.f) ? o.z : 0.2f * o.z;
            o.w = (o.w > 0.f) ? o.w : 0.2f * o.w;
            out4[(size_t)((b * F_ + f) * Dout_ + dout) * NCH + e] = o;
        }
    }
}

extern "C" void kernel_launch(void* const* d_in, const int* in_sizes, int n_in,
                              void* d_out, int out_size, void* d_ws, size_t ws_size,
                              hipStream_t stream) {
    const float* in = (const float*)d_in[0];
    const float* wt = (const float*)d_in[1];
    const float* bs = (const float*)d_in[2];
    float* out = (float*)d_out;
    float* bb = (float*)d_ws;   // F_ * PLANE floats = 122,880 B

    k_bb<<<dim3(F_), dim3(256), 0, stream>>>(bs, bb);
    // 752 blocks: bx = dout*8 + b  (b = bx&7 -> XCD affinity)
    k_main<<<dim3(B_ * Dout_), dim3(1024), 0, stream>>>(in, wt, bb, out);
}